// Round 21
// baseline (49.372 us; speedup 1.0000x reference)
//
#include <hip/hip_runtime.h>
#include <math.h>

#define NROWS 16384
#define DD 16
#define HH 128
#define NSUP 64            // 64 supertiles of 256 rows
#define NPAIRS 2080        // NSUP*(NSUP+1)/2
#define L2E 1.4426950408889634f
#define SQL2E 1.2011224087864498f   // sqrt(log2(e))

typedef __attribute__((ext_vector_type(8))) short v8s;   // 8 bf16 (MFMA A/B frag)
typedef __attribute__((ext_vector_type(4))) float v4f;   // MFMA C/D frag
typedef __attribute__((ext_vector_type(4))) unsigned int v4u;

__device__ __forceinline__ float softplus_f(float x) {
    return fmaxf(x, 0.0f) + log1pf(__expf(-fabsf(x)));
}
// Compiler-visible exp2 (TRANS op modeled). Opaque-asm v_exp_f32: banned (R4-R9).
// R12 lesson: exp argument must stay jointly bounded as hj+hk+dot.
__device__ __forceinline__ float exp2_b(float x) {
#if __has_builtin(__builtin_amdgcn_exp2f)
    return __builtin_amdgcn_exp2f(x);
#else
    return exp2f(x);
#endif
}
__device__ __forceinline__ unsigned short bf16_rne(float f) {
    unsigned int u = __float_as_uint(f);
    return (unsigned short)((u + 0x7FFFu + ((u >> 16) & 1u)) >> 16);
}

// prep: VERBATIM R17 (verified).
__global__ __launch_bounds__(512) void prep_kernel(
    const float* __restrict__ inputs,
    const float* __restrict__ W1, const float* __restrict__ b1,
    const float* __restrict__ Wm, const float* __restrict__ bm,
    const float* __restrict__ Ws, const float* __restrict__ bs,
    unsigned int* __restrict__ packed,
    float* __restrict__ hvals,
    float* __restrict__ tpart)
{
    __shared__ v4f sW1t4[HH * 4];
    __shared__ v4f sWm4[HH * 4], sWs4[HH * 4];
    __shared__ float sb1[HH];
    __shared__ float part[DD][512];
    int tid = threadIdx.x;

    {
        const v4f* gm = (const v4f*)Wm;
        const v4f* gs = (const v4f*)Ws;
        for (int i = tid; i < HH * 4; i += 512) { sWm4[i] = gm[i]; sWs4[i] = gs[i]; }
        float* sW1t = (float*)sW1t4;
        for (int i = tid; i < DD * HH; i += 512) {
            int d = i >> 7, u = i & 127;
            sW1t[u * DD + d] = W1[i];
        }
        if (tid < HH) sb1[tid] = b1[tid];
    }
    __syncthreads();

    int t = tid & 63, w = tid >> 6;
    int row = blockIdx.x * 64 + t;
    const float* rp = inputs + row * (1 + 2 * DD);
    float x[DD];
    #pragma unroll
    for (int d = 0; d < DD; ++d) x[d] = rp[1 + d];
    v4f m4[4], s4[4];
    #pragma unroll
    for (int q = 0; q < 4; ++q)
        #pragma unroll
        for (int r = 0; r < 4; ++r) { m4[q][r] = 0.0f; s4[q][r] = 0.0f; }

    int u0 = w * 16;
    for (int u = u0; u < u0 + 16; ++u) {
        v4f a0 = sW1t4[u * 4 + 0], a1 = sW1t4[u * 4 + 1];
        v4f a2 = sW1t4[u * 4 + 2], a3 = sW1t4[u * 4 + 3];
        float hv = sb1[u];
        #pragma unroll
        for (int r = 0; r < 4; ++r) hv = fmaf(x[r], a0[r], hv);
        #pragma unroll
        for (int r = 0; r < 4; ++r) hv = fmaf(x[4 + r], a1[r], hv);
        #pragma unroll
        for (int r = 0; r < 4; ++r) hv = fmaf(x[8 + r], a2[r], hv);
        #pragma unroll
        for (int r = 0; r < 4; ++r) hv = fmaf(x[12 + r], a3[r], hv);
        hv = fmaxf(hv, 0.0f);
        #pragma unroll
        for (int q = 0; q < 4; ++q) {
            v4f wm = sWm4[u * 4 + q], ws = sWs4[u * 4 + q];
            #pragma unroll
            for (int r = 0; r < 4; ++r) {
                m4[q][r] = fmaf(hv, wm[r], m4[q][r]);
                s4[q][r] = fmaf(hv, ws[r], s4[q][r]);
            }
        }
    }

    #pragma unroll
    for (int d = 0; d < DD; ++d) part[d][tid] = m4[d >> 2][d & 3];
    __syncthreads();
    float mm[DD];
    if (w == 0) {
        #pragma unroll
        for (int d = 0; d < DD; ++d) {
            mm[d] = ((part[d][t] + part[d][64 + t]) + (part[d][128 + t] + part[d][192 + t]))
                  + ((part[d][256 + t] + part[d][320 + t]) + (part[d][384 + t] + part[d][448 + t]))
                  + bm[d];
        }
    }
    __syncthreads();
    #pragma unroll
    for (int d = 0; d < DD; ++d) part[d][tid] = s4[d >> 2][d & 3];
    __syncthreads();

    if (w == 0) {
        float step = rp[0];
        float ss = sqrtf(step);
        float r2 = 0.0f;
        float smp[DD];
        #pragma unroll
        for (int d = 0; d < DD; ++d) {
            float sv = ((part[d][t] + part[d][64 + t]) + (part[d][128 + t] + part[d][192 + t]))
                     + ((part[d][256 + t] + part[d][320 + t]) + (part[d][384 + t] + part[d][448 + t]))
                     + bs[d];
            float sp = softplus_f(sv) + 0.001f;
            smp[d] = (rp[1 + DD + d] - (x[d] + step * mm[d])) / (ss * sp);
            r2 = fmaf(smp[d], smp[d], r2);
        }
        hvals[row] = -0.5f * r2 * L2E;

        float t1 = __expf(-0.25f * r2);
        #pragma unroll
        for (int off = 32; off > 0; off >>= 1) t1 += __shfl_down(t1, off);
        if (t == 0) tpart[blockIdx.x] = t1;

        unsigned short hs[DD], ls[DD];
        #pragma unroll
        for (int d = 0; d < DD; ++d) {
            float sp2 = smp[d] * SQL2E;
            unsigned short hi = bf16_rne(sp2);
            float rem = sp2 - __uint_as_float(((unsigned int)hi) << 16);
            hs[d] = hi;
            ls[d] = bf16_rne(rem);
        }
        unsigned int* prow = packed + row * 16;
        v4u q;
        q.x = hs[0] | (hs[1] << 16);  q.y = hs[2] | (hs[3] << 16);
        q.z = hs[4] | (hs[5] << 16);  q.w = hs[6] | (hs[7] << 16);
        *(v4u*)(prow + 0) = q;
        q.x = hs[8] | (hs[9] << 16);  q.y = hs[10] | (hs[11] << 16);
        q.z = hs[12] | (hs[13] << 16); q.w = hs[14] | (hs[15] << 16);
        *(v4u*)(prow + 4) = q;
        q.x = ls[0] | (ls[1] << 16);  q.y = ls[2] | (ls[3] << 16);
        q.z = ls[4] | (ls[5] << 16);  q.w = ls[6] | (ls[7] << 16);
        *(v4u*)(prow + 8) = q;
        q.x = ls[8] | (ls[9] << 16);  q.y = ls[10] | (ls[11] << 16);
        q.z = ls[12] | (ls[13] << 16); q.w = ls[14] | (ls[15] << 16);
        *(v4u*)(prow + 12) = q;
    }
}

// The verified R17 2-tt inner loop over a full 16-tt supertile, factored.
__device__ __forceinline__ float compute16(
    const v8s* skB8, const float* shk, const v8s* A1, const v8s* A2,
    const v4f* hj4, bool isdiag, int w, int myrow4, int col, int l)
{
    float sum0 = 0.0f, sum1 = 0.0f, sum2 = 0.0f, sum3 = 0.0f;

    #pragma unroll 2
    for (int tt = 0; tt < 16; tt += 2) {
        v8s Ba = skB8[tt * 64 + l];
        v8s Bb = skB8[(tt + 1) * 64 + l];
        float hka = shk[tt * 16 + col];
        float hkb = shk[(tt + 1) * 16 + col];

        #pragma unroll
        for (int fp = 0; fp < 2; ++fp) {
            const int f0 = 2 * fp, f1 = 2 * fp + 1;
            v4f c0a, c1a, c0b, c1b;
            #pragma unroll
            for (int r = 0; r < 4; ++r) {
                c0a[r] = hj4[f0][r] + hka; c1a[r] = hj4[f1][r] + hka;
                c0b[r] = hj4[f0][r] + hkb; c1b[r] = hj4[f1][r] + hkb;
            }
            c0a = __builtin_amdgcn_mfma_f32_16x16x32_bf16(A1[f0], Ba, c0a, 0, 0, 0);
            c1a = __builtin_amdgcn_mfma_f32_16x16x32_bf16(A1[f1], Ba, c1a, 0, 0, 0);
            c0b = __builtin_amdgcn_mfma_f32_16x16x32_bf16(A1[f0], Bb, c0b, 0, 0, 0);
            c1b = __builtin_amdgcn_mfma_f32_16x16x32_bf16(A1[f1], Bb, c1b, 0, 0, 0);
            c0a = __builtin_amdgcn_mfma_f32_16x16x32_bf16(A2[f0], Ba, c0a, 0, 0, 0);
            c1a = __builtin_amdgcn_mfma_f32_16x16x32_bf16(A2[f1], Ba, c1a, 0, 0, 0);
            c0b = __builtin_amdgcn_mfma_f32_16x16x32_bf16(A2[f0], Bb, c0b, 0, 0, 0);
            c1b = __builtin_amdgcn_mfma_f32_16x16x32_bf16(A2[f1], Bb, c1b, 0, 0, 0);

            float e0 = exp2_b(c0a[0]), e1 = exp2_b(c0a[1]);
            float e2 = exp2_b(c0a[2]), e3 = exp2_b(c0a[3]);
            float e4 = exp2_b(c1a[0]), e5 = exp2_b(c1a[1]);
            float e6 = exp2_b(c1a[2]), e7 = exp2_b(c1a[3]);
            float g0 = exp2_b(c0b[0]), g1 = exp2_b(c0b[1]);
            float g2 = exp2_b(c0b[2]), g3 = exp2_b(c0b[3]);
            float g4 = exp2_b(c1b[0]), g5 = exp2_b(c1b[1]);
            float g6 = exp2_b(c1b[2]), g7 = exp2_b(c1b[3]);

            if (isdiag) {
                if (tt == w * 4 + f0) {
                    if (myrow4 + 0 == col) e0 = 0.0f;
                    if (myrow4 + 1 == col) e1 = 0.0f;
                    if (myrow4 + 2 == col) e2 = 0.0f;
                    if (myrow4 + 3 == col) e3 = 0.0f;
                }
                if (tt == w * 4 + f1) {
                    if (myrow4 + 0 == col) e4 = 0.0f;
                    if (myrow4 + 1 == col) e5 = 0.0f;
                    if (myrow4 + 2 == col) e6 = 0.0f;
                    if (myrow4 + 3 == col) e7 = 0.0f;
                }
                if (tt + 1 == w * 4 + f0) {
                    if (myrow4 + 0 == col) g0 = 0.0f;
                    if (myrow4 + 1 == col) g1 = 0.0f;
                    if (myrow4 + 2 == col) g2 = 0.0f;
                    if (myrow4 + 3 == col) g3 = 0.0f;
                }
                if (tt + 1 == w * 4 + f1) {
                    if (myrow4 + 0 == col) g4 = 0.0f;
                    if (myrow4 + 1 == col) g5 = 0.0f;
                    if (myrow4 + 2 == col) g6 = 0.0f;
                    if (myrow4 + 3 == col) g7 = 0.0f;
                }
            }
            float esA0 = (e0 + e1) + (e2 + e3);
            float esA1 = (e4 + e5) + (e6 + e7);
            float esB0 = (g0 + g1) + (g2 + g3);
            float esB1 = (g4 + g5) + (g6 + g7);
            if (fp == 0) { sum0 += esA0 + esB0; sum1 += esA1 + esB1; }
            else         { sum2 += esA0 + esB0; sum3 += esA1 + esB1; }
        }
    }
    return (sum0 + sum1) + (sum2 + sum3);
}

// Dual-pair block: 1040 blocks, each computes pairs p=2g and p=2g+1.
// Consecutive p's share `a` except at row boundaries (block-uniform reload).
// K-tile for pair1 prefetched into regs during compute0 (latency hidden),
// written to LDS after the post-epilogue barrier.
__global__ __launch_bounds__(256, 2) void pair_kernel(
    const unsigned int* __restrict__ packed,
    const float* __restrict__ hvals,
    float* __restrict__ ppart)
{
    __shared__ unsigned short skB[8192];
    __shared__ float shk[256];
    __shared__ float shj[256];
    __shared__ float red[4];

    int tid = threadIdx.x;
    int l = tid & 63, w = tid >> 6;

    int p = (int)blockIdx.x * 2;
    int a0 = 0;
    while (p >= NSUP - a0) { p -= NSUP - a0; ++a0; }
    int b0 = a0 + p;
    int a1 = a0, b1 = b0 + 1;
    if (b1 >= NSUP) { a1 = a0 + 1; b1 = a1; }

    int col = l & 15;
    int sub = l >> 4;
    int myrow4 = sub * 4;

    const unsigned short* pk16 = (const unsigned short*)packed;

    // ---- stage pair0: shj(a0), shk(b0), K(b0), A(a0)
    shj[tid] = hvals[a0 * 256 + tid];
    shk[tid] = hvals[b0 * 256 + tid];
    int kb0 = b0 * 256;
    #pragma unroll
    for (int c = 0; c < 4; ++c) {
        int chunk = c * 256 + tid;
        int tt = chunk >> 6, l6 = chunk & 63;
        int rec = kb0 + tt * 16 + (l6 & 15);
        int sk = l6 >> 4;
        *(v8s*)(skB + chunk * 8) = *(const v8s*)(pk16 + (size_t)rec * 32 + sk * 8);
    }
    v8s A1[4], A2[4];
    #pragma unroll
    for (int f = 0; f < 4; ++f) {
        int jrow = a0 * 256 + w * 64 + f * 16 + col;
        A1[f] = *(const v8s*)(pk16 + (size_t)jrow * 32 + sub * 8);
        A2[f] = *(const v8s*)(pk16 + (size_t)jrow * 32 + (sub ^ 2) * 8);
    }
    __syncthreads();

    v4f hj4[4];
    #pragma unroll
    for (int f = 0; f < 4; ++f)
        hj4[f] = *(const v4f*)&shj[w * 64 + f * 16 + myrow4];

    // ---- issue K(b1) prefetch into regs (consumed after compute0)
    v8s pf[4];
    float pfhk;
    {
        int kb1 = b1 * 256;
        #pragma unroll
        for (int c = 0; c < 4; ++c) {
            int chunk = c * 256 + tid;
            int tt = chunk >> 6, l6 = chunk & 63;
            int rec = kb1 + tt * 16 + (l6 & 15);
            int sk = l6 >> 4;
            pf[c] = *(const v8s*)(pk16 + (size_t)rec * 32 + sk * 8);
        }
        pfhk = hvals[kb1 + tid];
    }

    // ---- compute pair0 + epilogue
    {
        float v = compute16((const v8s*)skB, shk, A1, A2, hj4, a0 == b0, w, myrow4, col, l);
        #pragma unroll
        for (int off = 32; off > 0; off >>= 1) v += __shfl_down(v, off);
        if (l == 0) red[w] = v;
        __syncthreads();
        if (tid == 0) {
            float wgt = (a0 == b0) ? 1.0f : 2.0f;
            ppart[(int)blockIdx.x * 2] = wgt * (red[0] + red[1] + red[2] + red[3]);
        }
        __syncthreads();   // all reads of skB/shk/red done before overwrite
    }

    // ---- stage pair1 (from regs) + A/hj reload iff row changed
    #pragma unroll
    for (int c = 0; c < 4; ++c)
        *(v8s*)(skB + (c * 256 + tid) * 8) = pf[c];
    shk[tid] = pfhk;
    if (a1 != a0) {
        shj[tid] = hvals[a1 * 256 + tid];
        #pragma unroll
        for (int f = 0; f < 4; ++f) {
            int jrow = a1 * 256 + w * 64 + f * 16 + col;
            A1[f] = *(const v8s*)(pk16 + (size_t)jrow * 32 + sub * 8);
            A2[f] = *(const v8s*)(pk16 + (size_t)jrow * 32 + (sub ^ 2) * 8);
        }
    }
    __syncthreads();
    if (a1 != a0) {
        #pragma unroll
        for (int f = 0; f < 4; ++f)
            hj4[f] = *(const v4f*)&shj[w * 64 + f * 16 + myrow4];
    }

    // ---- compute pair1 + epilogue
    {
        float v = compute16((const v8s*)skB, shk, A1, A2, hj4, a1 == b1, w, myrow4, col, l);
        #pragma unroll
        for (int off = 32; off > 0; off >>= 1) v += __shfl_down(v, off);
        if (l == 0) red[w] = v;
        __syncthreads();
        if (tid == 0) {
            float wgt = (a1 == b1) ? 1.0f : 2.0f;
            ppart[(int)blockIdx.x * 2 + 1] = wgt * (red[0] + red[1] + red[2] + red[3]);
        }
    }
}

// final: VERBATIM R17 (verified), NPAIRS partials.
__global__ __launch_bounds__(256) void final_kernel(
    const float* __restrict__ ppart, const float* __restrict__ tpart,
    float* __restrict__ out)
{
    __shared__ float reds[4], redt[4];
    int tid = threadIdx.x;
    int l = tid & 63, w = tid >> 6;

    float s = 0.0f;
    for (int i = tid; i < NPAIRS; i += 256) s += ppart[i];
    float t = tpart[tid];

    #pragma unroll
    for (int off = 32; off > 0; off >>= 1) {
        s += __shfl_down(s, off);
        t += __shfl_down(t, off);
    }
    if (l == 0) { reds[w] = s; redt[w] = t; }
    __syncthreads();
    if (tid == 0) {
        float S = (reds[0] + reds[1]) + (reds[2] + reds[3]);
        float T = (redt[0] + redt[1]) + (redt[2] + redt[3]);
        float n = (float)NROWS;
        // +n = exact diagonal (exp(0) per row), masked out of the pair sum
        out[0] = (S + n) / n - 0.0078125f * T + n * (1.0f / 6561.0f);
    }
}

extern "C" void kernel_launch(void* const* d_in, const int* in_sizes, int n_in,
                              void* d_out, int out_size, void* d_ws, size_t ws_size,
                              hipStream_t stream)
{
    const float* inputs = (const float*)d_in[0];
    const float* W1 = (const float*)d_in[1];
    const float* b1 = (const float*)d_in[2];
    const float* Wm = (const float*)d_in[3];
    const float* bm = (const float*)d_in[4];
    const float* Ws = (const float*)d_in[5];
    const float* bs = (const float*)d_in[6];

    float* tpart         = (float*)((char*)d_ws + 256);                 // 256 floats
    float* ppart         = (float*)((char*)d_ws + 256 + 1024);          // 2080 floats
    float* hvals         = (float*)((char*)d_ws + 256 + 1024 + 8448);   // 16384 floats
    unsigned int* packed = (unsigned int*)((char*)d_ws + 256 + 1024 + 8448 + 65536); // 1 MB

    prep_kernel<<<NROWS / 64, 512, 0, stream>>>(inputs, W1, b1, Wm, bm, Ws, bs,
                                                packed, hvals, tpart);
    pair_kernel<<<NPAIRS / 2, 256, 0, stream>>>(packed, hvals, ppart);
    final_kernel<<<1, 256, 0, stream>>>(ppart, tpart, (float*)d_out);
}

// Round 22
// 45.334 us; speedup vs baseline: 1.0891x; 1.0891x over previous
//
#include <hip/hip_runtime.h>
#include <math.h>

#define NROWS 16384
#define DD 16
#define HH 128
#define NSUP 64            // 64 supertiles of 256 rows
#define NPAIRS 2080        // NSUP*(NSUP+1)/2
#define L2E 1.4426950408889634f
#define SQL2E 1.2011224087864498f   // sqrt(log2(e))

typedef __attribute__((ext_vector_type(8))) short v8s;   // 8 bf16 (MFMA A/B frag)
typedef __attribute__((ext_vector_type(4))) float v4f;   // MFMA C/D frag
typedef __attribute__((ext_vector_type(4))) unsigned int v4u;

__device__ __forceinline__ float softplus_f(float x) {
    return fmaxf(x, 0.0f) + log1pf(__expf(-fabsf(x)));
}
// Compiler-visible exp2 (TRANS op modeled). Opaque-asm v_exp_f32: banned (R4-R9).
// R12 lesson: exp argument must stay jointly bounded as hj+hk+dot.
__device__ __forceinline__ float exp2_b(float x) {
#if __has_builtin(__builtin_amdgcn_exp2f)
    return __builtin_amdgcn_exp2f(x);
#else
    return exp2f(x);
#endif
}
__device__ __forceinline__ unsigned short bf16_rne(float f) {
    unsigned int u = __float_as_uint(f);
    return (unsigned short)((u + 0x7FFFu + ((u >> 16) & 1u)) >> 16);
}

// prep: VERBATIM R17 (verified).
__global__ __launch_bounds__(512) void prep_kernel(
    const float* __restrict__ inputs,
    const float* __restrict__ W1, const float* __restrict__ b1,
    const float* __restrict__ Wm, const float* __restrict__ bm,
    const float* __restrict__ Ws, const float* __restrict__ bs,
    unsigned int* __restrict__ packed,
    float* __restrict__ hvals,
    float* __restrict__ tpart)
{
    __shared__ v4f sW1t4[HH * 4];
    __shared__ v4f sWm4[HH * 4], sWs4[HH * 4];
    __shared__ float sb1[HH];
    __shared__ float part[DD][512];
    int tid = threadIdx.x;

    {
        const v4f* gm = (const v4f*)Wm;
        const v4f* gs = (const v4f*)Ws;
        for (int i = tid; i < HH * 4; i += 512) { sWm4[i] = gm[i]; sWs4[i] = gs[i]; }
        float* sW1t = (float*)sW1t4;
        for (int i = tid; i < DD * HH; i += 512) {
            int d = i >> 7, u = i & 127;
            sW1t[u * DD + d] = W1[i];
        }
        if (tid < HH) sb1[tid] = b1[tid];
    }
    __syncthreads();

    int t = tid & 63, w = tid >> 6;
    int row = blockIdx.x * 64 + t;
    const float* rp = inputs + row * (1 + 2 * DD);
    float x[DD];
    #pragma unroll
    for (int d = 0; d < DD; ++d) x[d] = rp[1 + d];
    v4f m4[4], s4[4];
    #pragma unroll
    for (int q = 0; q < 4; ++q)
        #pragma unroll
        for (int r = 0; r < 4; ++r) { m4[q][r] = 0.0f; s4[q][r] = 0.0f; }

    int u0 = w * 16;
    for (int u = u0; u < u0 + 16; ++u) {
        v4f a0 = sW1t4[u * 4 + 0], a1 = sW1t4[u * 4 + 1];
        v4f a2 = sW1t4[u * 4 + 2], a3 = sW1t4[u * 4 + 3];
        float hv = sb1[u];
        #pragma unroll
        for (int r = 0; r < 4; ++r) hv = fmaf(x[r], a0[r], hv);
        #pragma unroll
        for (int r = 0; r < 4; ++r) hv = fmaf(x[4 + r], a1[r], hv);
        #pragma unroll
        for (int r = 0; r < 4; ++r) hv = fmaf(x[8 + r], a2[r], hv);
        #pragma unroll
        for (int r = 0; r < 4; ++r) hv = fmaf(x[12 + r], a3[r], hv);
        hv = fmaxf(hv, 0.0f);
        #pragma unroll
        for (int q = 0; q < 4; ++q) {
            v4f wm = sWm4[u * 4 + q], ws = sWs4[u * 4 + q];
            #pragma unroll
            for (int r = 0; r < 4; ++r) {
                m4[q][r] = fmaf(hv, wm[r], m4[q][r]);
                s4[q][r] = fmaf(hv, ws[r], s4[q][r]);
            }
        }
    }

    #pragma unroll
    for (int d = 0; d < DD; ++d) part[d][tid] = m4[d >> 2][d & 3];
    __syncthreads();
    float mm[DD];
    if (w == 0) {
        #pragma unroll
        for (int d = 0; d < DD; ++d) {
            mm[d] = ((part[d][t] + part[d][64 + t]) + (part[d][128 + t] + part[d][192 + t]))
                  + ((part[d][256 + t] + part[d][320 + t]) + (part[d][384 + t] + part[d][448 + t]))
                  + bm[d];
        }
    }
    __syncthreads();
    #pragma unroll
    for (int d = 0; d < DD; ++d) part[d][tid] = s4[d >> 2][d & 3];
    __syncthreads();

    if (w == 0) {
        float step = rp[0];
        float ss = sqrtf(step);
        float r2 = 0.0f;
        float smp[DD];
        #pragma unroll
        for (int d = 0; d < DD; ++d) {
            float sv = ((part[d][t] + part[d][64 + t]) + (part[d][128 + t] + part[d][192 + t]))
                     + ((part[d][256 + t] + part[d][320 + t]) + (part[d][384 + t] + part[d][448 + t]))
                     + bs[d];
            float sp = softplus_f(sv) + 0.001f;
            smp[d] = (rp[1 + DD + d] - (x[d] + step * mm[d])) / (ss * sp);
            r2 = fmaf(smp[d], smp[d], r2);
        }
        hvals[row] = -0.5f * r2 * L2E;

        float t1 = __expf(-0.25f * r2);
        #pragma unroll
        for (int off = 32; off > 0; off >>= 1) t1 += __shfl_down(t1, off);
        if (t == 0) tpart[blockIdx.x] = t1;

        unsigned short hs[DD], ls[DD];
        #pragma unroll
        for (int d = 0; d < DD; ++d) {
            float sp2 = smp[d] * SQL2E;
            unsigned short hi = bf16_rne(sp2);
            float rem = sp2 - __uint_as_float(((unsigned int)hi) << 16);
            hs[d] = hi;
            ls[d] = bf16_rne(rem);
        }
        unsigned int* prow = packed + row * 16;
        v4u q;
        q.x = hs[0] | (hs[1] << 16);  q.y = hs[2] | (hs[3] << 16);
        q.z = hs[4] | (hs[5] << 16);  q.w = hs[6] | (hs[7] << 16);
        *(v4u*)(prow + 0) = q;
        q.x = hs[8] | (hs[9] << 16);  q.y = hs[10] | (hs[11] << 16);
        q.z = hs[12] | (hs[13] << 16); q.w = hs[14] | (hs[15] << 16);
        *(v4u*)(prow + 4) = q;
        q.x = ls[0] | (ls[1] << 16);  q.y = ls[2] | (ls[3] << 16);
        q.z = ls[4] | (ls[5] << 16);  q.w = ls[6] | (ls[7] << 16);
        *(v4u*)(prow + 8) = q;
        q.x = ls[8] | (ls[9] << 16);  q.y = ls[10] | (ls[11] << 16);
        q.z = ls[12] | (ls[13] << 16); q.w = ls[14] | (ls[15] << 16);
        *(v4u*)(prow + 12) = q;
    }
}

// Pair kernel: VERBATIM R17 (verified best, 45.9us total). 2-tt interleave,
// block partial store. R18 4-tt: spill (VGPR=128, 58MB scratch). R19 fusion:
// codegen perturbation (VGPR 68, chains serialized). R20 k-split / R21
// dual-pair: prologue economics worse. This structure is the measured optimum.
__global__ __launch_bounds__(256, 2) void pair_kernel(
    const unsigned int* __restrict__ packed,
    const float* __restrict__ hvals,
    float* __restrict__ ppart)
{
    __shared__ unsigned short skB[8192];
    __shared__ float shk[256];
    __shared__ float shj[256];
    __shared__ float red[4];

    int tid = threadIdx.x;
    int l = tid & 63, w = tid >> 6;

    int p = blockIdx.x;
    int a = 0;
    while (p >= NSUP - a) { p -= NSUP - a; ++a; }
    int b = a + p;
    bool isdiag = (a == b);

    int jbase = a * 256 + w * 64;
    int kb = b * 256;

    int col = l & 15;
    int sub = l >> 4;
    int myrow4 = sub * 4;

    const unsigned short* pk16 = (const unsigned short*)packed;

    shj[tid] = hvals[a * 256 + tid];
    shk[tid] = hvals[kb + tid];
    #pragma unroll
    for (int c = 0; c < 4; ++c) {
        int chunk = c * 256 + tid;
        int tt = chunk >> 6, l6 = chunk & 63;
        int rec = kb + tt * 16 + (l6 & 15);
        int sk = l6 >> 4;
        v8s v = *(const v8s*)(pk16 + (size_t)rec * 32 + sk * 8);
        *(v8s*)(skB + chunk * 8) = v;
    }

    v8s A1[4], A2[4];
    #pragma unroll
    for (int f = 0; f < 4; ++f) {
        int jrow = jbase + f * 16 + col;
        A1[f] = *(const v8s*)(pk16 + (size_t)jrow * 32 + sub * 8);
        A2[f] = *(const v8s*)(pk16 + (size_t)jrow * 32 + (sub ^ 2) * 8);
    }
    __syncthreads();

    v4f hj4[4];
    #pragma unroll
    for (int f = 0; f < 4; ++f)
        hj4[f] = *(const v4f*)&shj[w * 64 + f * 16 + myrow4];

    float sum0 = 0.0f, sum1 = 0.0f, sum2 = 0.0f, sum3 = 0.0f;
    const v8s* skB8 = (const v8s*)skB;

    #pragma unroll 2
    for (int tt = 0; tt < 16; tt += 2) {
        v8s Ba = skB8[tt * 64 + l];
        v8s Bb = skB8[(tt + 1) * 64 + l];
        float hka = shk[tt * 16 + col];
        float hkb = shk[(tt + 1) * 16 + col];

        #pragma unroll
        for (int fp = 0; fp < 2; ++fp) {
            const int f0 = 2 * fp, f1 = 2 * fp + 1;
            v4f c0a, c1a, c0b, c1b;
            #pragma unroll
            for (int r = 0; r < 4; ++r) {
                c0a[r] = hj4[f0][r] + hka; c1a[r] = hj4[f1][r] + hka;
                c0b[r] = hj4[f0][r] + hkb; c1b[r] = hj4[f1][r] + hkb;
            }
            c0a = __builtin_amdgcn_mfma_f32_16x16x32_bf16(A1[f0], Ba, c0a, 0, 0, 0);
            c1a = __builtin_amdgcn_mfma_f32_16x16x32_bf16(A1[f1], Ba, c1a, 0, 0, 0);
            c0b = __builtin_amdgcn_mfma_f32_16x16x32_bf16(A1[f0], Bb, c0b, 0, 0, 0);
            c1b = __builtin_amdgcn_mfma_f32_16x16x32_bf16(A1[f1], Bb, c1b, 0, 0, 0);
            c0a = __builtin_amdgcn_mfma_f32_16x16x32_bf16(A2[f0], Ba, c0a, 0, 0, 0);
            c1a = __builtin_amdgcn_mfma_f32_16x16x32_bf16(A2[f1], Ba, c1a, 0, 0, 0);
            c0b = __builtin_amdgcn_mfma_f32_16x16x32_bf16(A2[f0], Bb, c0b, 0, 0, 0);
            c1b = __builtin_amdgcn_mfma_f32_16x16x32_bf16(A2[f1], Bb, c1b, 0, 0, 0);

            float e0 = exp2_b(c0a[0]), e1 = exp2_b(c0a[1]);
            float e2 = exp2_b(c0a[2]), e3 = exp2_b(c0a[3]);
            float e4 = exp2_b(c1a[0]), e5 = exp2_b(c1a[1]);
            float e6 = exp2_b(c1a[2]), e7 = exp2_b(c1a[3]);
            float g0 = exp2_b(c0b[0]), g1 = exp2_b(c0b[1]);
            float g2 = exp2_b(c0b[2]), g3 = exp2_b(c0b[3]);
            float g4 = exp2_b(c1b[0]), g5 = exp2_b(c1b[1]);
            float g6 = exp2_b(c1b[2]), g7 = exp2_b(c1b[3]);

            if (isdiag) {
                if (tt == w * 4 + f0) {
                    if (myrow4 + 0 == col) e0 = 0.0f;
                    if (myrow4 + 1 == col) e1 = 0.0f;
                    if (myrow4 + 2 == col) e2 = 0.0f;
                    if (myrow4 + 3 == col) e3 = 0.0f;
                }
                if (tt == w * 4 + f1) {
                    if (myrow4 + 0 == col) e4 = 0.0f;
                    if (myrow4 + 1 == col) e5 = 0.0f;
                    if (myrow4 + 2 == col) e6 = 0.0f;
                    if (myrow4 + 3 == col) e7 = 0.0f;
                }
                if (tt + 1 == w * 4 + f0) {
                    if (myrow4 + 0 == col) g0 = 0.0f;
                    if (myrow4 + 1 == col) g1 = 0.0f;
                    if (myrow4 + 2 == col) g2 = 0.0f;
                    if (myrow4 + 3 == col) g3 = 0.0f;
                }
                if (tt + 1 == w * 4 + f1) {
                    if (myrow4 + 0 == col) g4 = 0.0f;
                    if (myrow4 + 1 == col) g5 = 0.0f;
                    if (myrow4 + 2 == col) g6 = 0.0f;
                    if (myrow4 + 3 == col) g7 = 0.0f;
                }
            }
            float esA0 = (e0 + e1) + (e2 + e3);
            float esA1 = (e4 + e5) + (e6 + e7);
            float esB0 = (g0 + g1) + (g2 + g3);
            float esB1 = (g4 + g5) + (g6 + g7);
            if (fp == 0) { sum0 += esA0 + esB0; sum1 += esA1 + esB1; }
            else         { sum2 += esA0 + esB0; sum3 += esA1 + esB1; }
        }
    }

    float v = (sum0 + sum1) + (sum2 + sum3);
    #pragma unroll
    for (int off = 32; off > 0; off >>= 1) v += __shfl_down(v, off);
    if (l == 0) red[w] = v;
    __syncthreads();
    if (tid == 0) {
        float wgt = isdiag ? 1.0f : 2.0f;
        ppart[blockIdx.x] = wgt * (red[0] + red[1] + red[2] + red[3]);
    }
}

// final: VERBATIM R17 (verified).
__global__ __launch_bounds__(256) void final_kernel(
    const float* __restrict__ ppart, const float* __restrict__ tpart,
    float* __restrict__ out)
{
    __shared__ float reds[4], redt[4];
    int tid = threadIdx.x;
    int l = tid & 63, w = tid >> 6;

    float s = 0.0f;
    for (int i = tid; i < NPAIRS; i += 256) s += ppart[i];
    float t = tpart[tid];

    #pragma unroll
    for (int off = 32; off > 0; off >>= 1) {
        s += __shfl_down(s, off);
        t += __shfl_down(t, off);
    }
    if (l == 0) { reds[w] = s; redt[w] = t; }
    __syncthreads();
    if (tid == 0) {
        float S = (reds[0] + reds[1]) + (reds[2] + reds[3]);
        float T = (redt[0] + redt[1]) + (redt[2] + redt[3]);
        float n = (float)NROWS;
        // +n = exact diagonal (exp(0) per row), masked out of the pair sum
        out[0] = (S + n) / n - 0.0078125f * T + n * (1.0f / 6561.0f);
    }
}

extern "C" void kernel_launch(void* const* d_in, const int* in_sizes, int n_in,
                              void* d_out, int out_size, void* d_ws, size_t ws_size,
                              hipStream_t stream)
{
    const float* inputs = (const float*)d_in[0];
    const float* W1 = (const float*)d_in[1];
    const float* b1 = (const float*)d_in[2];
    const float* Wm = (const float*)d_in[3];
    const float* bm = (const float*)d_in[4];
    const float* Ws = (const float*)d_in[5];
    const float* bs = (const float*)d_in[6];

    float* tpart         = (float*)((char*)d_ws + 256);                 // 256 floats
    float* ppart         = (float*)((char*)d_ws + 256 + 1024);          // 2080 floats
    float* hvals         = (float*)((char*)d_ws + 256 + 1024 + 8448);   // 16384 floats
    unsigned int* packed = (unsigned int*)((char*)d_ws + 256 + 1024 + 8448 + 65536); // 1 MB

    prep_kernel<<<NROWS / 64, 512, 0, stream>>>(inputs, W1, b1, Wm, bm, Ws, bs,
                                                packed, hvals, tpart);
    pair_kernel<<<NPAIRS, 256, 0, stream>>>(packed, hvals, ppart);
    final_kernel<<<1, 256, 0, stream>>>(ppart, tpart, (float*)d_out);
}